// Round 7
// baseline (194.339 us; speedup 1.0000x reference)
//
#include <hip/hip_runtime.h>

// RNN_53214644797476: out = tanh(X @ W^T + hs @ H^T), hs never updated.
// => one GEMM [32768,1024]x[1024,1024]^T + tiny h_term + tanh epilogue.
// Round 7: BK 32 -> 64 (halves the 2-phase loop's barrier/drain count, the
// measured structural cost; 32 MFMA per wave per barrier pair). LDS 32 KB
// still allows 4 blocks/CU; frags reloaded per kk-half keep VGPR ~60.
// Pre-swizzle deepened to 8-slot groups (sd = st ^ (row&7) within 8-group)
// because BK=64 rows are 128 B (all rows bank-aligned); read XOR matches.
// Prep kept from round 6 (one work-item per thread, ~BW-floor).

typedef __bf16 bf16x8 __attribute__((ext_vector_type(8)));
typedef float f32x4 __attribute__((ext_vector_type(4)));
typedef unsigned short us4 __attribute__((ext_vector_type(4)));

constexpr int M_TOT = 32768;  // SEQ*BATCH
constexpr int K_D = 1024;
constexpr int N_D = 1024;
constexpr int BK = 64;

__device__ __forceinline__ void async16(const void* g, void* l) {
  __builtin_amdgcn_global_load_lds(
      (const __attribute__((address_space(1))) unsigned int*)g,
      (__attribute__((address_space(3))) unsigned int*)l, 16, 0, 0);
}

__device__ __forceinline__ unsigned short f2bf(float f) {
  unsigned int u = __float_as_uint(f);
  u += 0x7FFFu + ((u >> 16) & 1u);  // round-to-nearest-even
  return (unsigned short)(u >> 16);
}

// ---- merged prep ----
// blocks [0, XBLK): X cvt, one float4 (= half of a 16B slot) per thread
// blocks [XBLK, XBLK+WBLK): W cvt, same
// blocks [XBLK+WBLK, +HBLK): h_term, one block per h
// Slot pre-swizzle (must match gemm read XOR): 16B slot st of row stored at
// sd = (st&~7) | ((st&7) ^ (row&7)).
constexpr int PREP_XBLK = M_TOT * K_D / 4 / 256;  // 32768
constexpr int PREP_WBLK = N_D * K_D / 4 / 256;    // 1024
constexpr int PREP_HBLK = 1024;
constexpr int PREP_GRID = PREP_XBLK + PREP_WBLK + PREP_HBLK;

__global__ __launch_bounds__(256) void prep_kernel(
    const float* __restrict__ X, unsigned short* __restrict__ Xbf,
    const float* __restrict__ W, unsigned short* __restrict__ Wbf,
    const float* __restrict__ hs, const float* __restrict__ Hm,
    float* __restrict__ ht) {
  __shared__ float4 Hrow4[256];
  const int b = blockIdx.x;
  const int tid = threadIdx.x;

  if (b < PREP_XBLK + PREP_WBLK) {
    const float* in = (b < PREP_XBLK) ? X : W;
    unsigned short* out = (b < PREP_XBLK) ? Xbf : Wbf;
    int j = (b < PREP_XBLK) ? (b * 256 + tid) : ((b - PREP_XBLK) * 256 + tid);
    // j indexes half-slots (4 floats each).
    int slot = j >> 1, half = j & 1;
    int row = slot >> 7, st = slot & 127;
    int sd = (st & ~7) | ((st & 7) ^ (row & 7));
    float4 a = *reinterpret_cast<const float4*>(in + (size_t)j * 4);
    us4 v;
    v[0] = f2bf(a.x); v[1] = f2bf(a.y); v[2] = f2bf(a.z); v[3] = f2bf(a.w);
    *reinterpret_cast<us4*>(out + (size_t)row * 1024 + sd * 8 + half * 4) = v;
  } else {
    // h_term[bb][h] = sum_k hs[bb][k] * Hm[h][k]
    int h = b - (PREP_XBLK + PREP_WBLK);
    Hrow4[tid] = reinterpret_cast<const float4*>(Hm + (size_t)h * 1024)[tid];
    __syncthreads();
    int w = tid >> 6, l = tid & 63;
#pragma unroll 2
    for (int bb = w * 16; bb < w * 16 + 16; ++bb) {
      const float4* hb4 = reinterpret_cast<const float4*>(hs + (size_t)bb * 1024);
      float s = 0.f;
#pragma unroll
      for (int p = 0; p < 4; ++p) {
        float4 x = hb4[l + p * 64];
        float4 y = Hrow4[l + p * 64];
        s += x.x * y.x + x.y * y.y + x.z * y.z + x.w * y.w;
      }
#pragma unroll
      for (int off = 32; off > 0; off >>= 1) s += __shfl_down(s, off, 64);
      if (l == 0) ht[bb * 1024 + h] = s;
    }
  }
}

// ---- main GEMM: C = tanh(A.B^T + ht[m%64][n]), BK=64 ----
__global__ __launch_bounds__(256, 4) void gemm_tanh(
    const unsigned short* __restrict__ A, const unsigned short* __restrict__ B,
    const float* __restrict__ ht, float* __restrict__ out0,
    float* __restrict__ out1) {
  __shared__ unsigned short As[128 * BK];  // 16 KiB
  __shared__ unsigned short Bs[128 * BK];  // 16 KiB

  // XCD-bijective swizzle (nwg = 2048 % 8 == 0); A-panel sharers co-XCD.
  int bid = blockIdx.x;
  int swz = (bid & 7) * 256 + (bid >> 3);
  int bm = swz >> 3;  // 0..255
  int bn = swz & 7;   // 0..7

  int tid = threadIdx.x;
  int lane = tid & 63, wid = tid >> 6;
  int wr = wid >> 1, wc = wid & 1;
  int fr = lane & 15, kq = lane >> 4;

  // Staging: 128x64 tile = 1024 x 16B chunks; chunk c -> row c>>3, slot c&7.
  // LDS dest linear; global source pre-swizzled, so source addrs are linear.
  const unsigned short* gA[4];
  const unsigned short* gB[4];
#pragma unroll
  for (int i = 0; i < 4; ++i) {
    int c = tid + i * 256;
    gA[i] = A + (size_t)(bm * 128 + (c >> 3)) * 1024 + (c & 7) * 8;
    gB[i] = B + (size_t)(bn * 128 + (c >> 3)) * 1024 + (c & 7) * 8;
  }

  f32x4 acc[4][4] = {};

  for (int ks = 0; ks < K_D; ks += BK) {
#pragma unroll
    for (int i = 0; i < 4; ++i) {
      async16(gA[i] + ks, &As[(tid + i * 256) * 8]);
      async16(gB[i] + ks, &Bs[(tid + i * 256) * 8]);
    }
    __syncthreads();  // drains vmcnt+lgkmcnt before LDS reads

#pragma unroll
    for (int kk = 0; kk < 2; ++kk) {
      bf16x8 af[4], bg[4];
#pragma unroll
      for (int mi = 0; mi < 4; ++mi) {
        int ra = wr * 64 + mi * 16 + fr;
        af[mi] = *reinterpret_cast<const bf16x8*>(
            &As[ra * BK + ((kk * 4 + kq) ^ (ra & 7)) * 8]);
      }
#pragma unroll
      for (int ni = 0; ni < 4; ++ni) {
        int rb = wc * 64 + ni * 16 + fr;
        bg[ni] = *reinterpret_cast<const bf16x8*>(
            &Bs[rb * BK + ((kk * 4 + kq) ^ (rb & 7)) * 8]);
      }
#pragma unroll
      for (int mi = 0; mi < 4; ++mi)
#pragma unroll
        for (int ni = 0; ni < 4; ++ni)
          acc[mi][ni] = __builtin_amdgcn_mfma_f32_16x16x32_bf16(
              af[mi], bg[ni], acc[mi][ni], 0, 0, 0);
    }
    __syncthreads();  // before next stage overwrites LDS
  }

  // Epilogue: y = tanh(acc + ht[m%64][n]); out0 always, out1 for last 64 rows.
  const int nbase = bn * 128 + wc * 64;
#pragma unroll
  for (int mi = 0; mi < 4; ++mi) {
#pragma unroll
    for (int r = 0; r < 4; ++r) {
      int mloc = wr * 64 + mi * 16 + kq * 4 + r;
      size_t m = (size_t)bm * 128 + mloc;
      int b = mloc & 63;
#pragma unroll
      for (int ni = 0; ni < 4; ++ni) {
        int n = nbase + ni * 16 + fr;
        float x = acc[mi][ni][r] + ht[b * 1024 + n];
        float e = __expf(2.0f * x);
        float y = 1.0f - 2.0f / (e + 1.0f);  // tanh(x), safe at +-inf
        out0[m * 1024 + n] = y;
        if (m >= (size_t)(M_TOT - 64))
          out1[(m - (M_TOT - 64)) * 1024 + n] = y;
      }
    }
  }
}

extern "C" void kernel_launch(void* const* d_in, const int* in_sizes, int n_in,
                              void* d_out, int out_size, void* d_ws,
                              size_t ws_size, hipStream_t stream) {
  (void)in_sizes; (void)n_in; (void)out_size; (void)ws_size;
  const float* X  = (const float*)d_in[0];  // [512,64,1024] = [32768,1024]
  const float* hs = (const float*)d_in[1];  // [64,1024]
  const float* W  = (const float*)d_in[2];  // [1024,1024]
  const float* Hm = (const float*)d_in[3];  // [1024,1024]
  float* out0 = (float*)d_out;               // [32768,1024]
  float* out1 = out0 + (size_t)M_TOT * N_D;  // [64,1024]

  // ws layout: Xbf (64 MiB) | Wbf (2 MiB) | hterm (256 KiB)
  unsigned short* Xbf = (unsigned short*)d_ws;
  unsigned short* Wbf = Xbf + (size_t)M_TOT * K_D;
  float* hterm = (float*)(Wbf + (size_t)N_D * K_D);

  prep_kernel<<<PREP_GRID, 256, 0, stream>>>(X, Xbf, W, Wbf, hs, Hm, hterm);
  gemm_tanh<<<(M_TOT / 128) * (N_D / 128), 256, 0, stream>>>(Xbf, Wbf, hterm,
                                                             out0, out1);
}

// Round 8
// 157.104 us; speedup vs baseline: 1.2370x; 1.2370x over previous
//
#include <hip/hip_runtime.h>

// RNN_53214644797476: out = tanh(X @ W^T + hs @ H^T), hs never updated.
// => one GEMM [32768,1024]x[1024,1024]^T + tiny h_term + tanh epilogue.
// Round 8: revert to round-6's measured-best scheduling (BK=32, single LDS
// buffer, 2 barriers/K-step, 4-group pre-swizzle, gload_lds staging) and
// change ONLY the tile aspect: 256x128 (BM=256) with 8 waves/512 threads,
// wave tile still 64x64 (acc[4][4], VGPR ~64). 2 blocks/CU x 8 waves =
// 16 waves/CU (same as R6's 4x4). Cuts logical staging reads 25% and
// halves barrier-drain events. Prep identical to round 6.

typedef __bf16 bf16x8 __attribute__((ext_vector_type(8)));
typedef float f32x4 __attribute__((ext_vector_type(4)));
typedef unsigned short us4 __attribute__((ext_vector_type(4)));

constexpr int M_TOT = 32768;  // SEQ*BATCH
constexpr int K_D = 1024;
constexpr int N_D = 1024;
constexpr int BM = 256, BN = 128, BKT = 32;

__device__ __forceinline__ void async16(const void* g, void* l) {
  __builtin_amdgcn_global_load_lds(
      (const __attribute__((address_space(1))) unsigned int*)g,
      (__attribute__((address_space(3))) unsigned int*)l, 16, 0, 0);
}

__device__ __forceinline__ unsigned short f2bf(float f) {
  unsigned int u = __float_as_uint(f);
  u += 0x7FFFu + ((u >> 16) & 1u);  // round-to-nearest-even
  return (unsigned short)(u >> 16);
}

// ---- merged prep (identical to round 6) ----
// blocks [0, XBLK): X cvt, one float4 per thread; [XBLK,+WBLK): W cvt;
// [XBLK+WBLK,+HBLK): h_term, one block per h.
// Slot pre-swizzle (matches gemm read XOR): 16B slot st of row stored at
// sd = (st&~3) | ((st&3) ^ ((row>>1)&3)).
constexpr int PREP_XBLK = M_TOT * K_D / 4 / 256;  // 32768
constexpr int PREP_WBLK = N_D * K_D / 4 / 256;    // 1024
constexpr int PREP_HBLK = 1024;
constexpr int PREP_GRID = PREP_XBLK + PREP_WBLK + PREP_HBLK;

__global__ __launch_bounds__(256) void prep_kernel(
    const float* __restrict__ X, unsigned short* __restrict__ Xbf,
    const float* __restrict__ W, unsigned short* __restrict__ Wbf,
    const float* __restrict__ hs, const float* __restrict__ Hm,
    float* __restrict__ ht) {
  __shared__ float4 Hrow4[256];
  const int b = blockIdx.x;
  const int tid = threadIdx.x;

  if (b < PREP_XBLK + PREP_WBLK) {
    const float* in = (b < PREP_XBLK) ? X : W;
    unsigned short* out = (b < PREP_XBLK) ? Xbf : Wbf;
    int j = (b < PREP_XBLK) ? (b * 256 + tid) : ((b - PREP_XBLK) * 256 + tid);
    // j indexes half-slots (4 floats each).
    int slot = j >> 1, half = j & 1;
    int row = slot >> 7, st = slot & 127;
    int sd = (st & ~3) | ((st & 3) ^ ((row >> 1) & 3));
    float4 a = *reinterpret_cast<const float4*>(in + (size_t)j * 4);
    us4 v;
    v[0] = f2bf(a.x); v[1] = f2bf(a.y); v[2] = f2bf(a.z); v[3] = f2bf(a.w);
    *reinterpret_cast<us4*>(out + (size_t)row * 1024 + sd * 8 + half * 4) = v;
  } else {
    // h_term[bb][h] = sum_k hs[bb][k] * Hm[h][k]
    int h = b - (PREP_XBLK + PREP_WBLK);
    Hrow4[tid] = reinterpret_cast<const float4*>(Hm + (size_t)h * 1024)[tid];
    __syncthreads();
    int w = tid >> 6, l = tid & 63;
#pragma unroll 2
    for (int bb = w * 16; bb < w * 16 + 16; ++bb) {
      const float4* hb4 = reinterpret_cast<const float4*>(hs + (size_t)bb * 1024);
      float s = 0.f;
#pragma unroll
      for (int p = 0; p < 4; ++p) {
        float4 x = hb4[l + p * 64];
        float4 y = Hrow4[l + p * 64];
        s += x.x * y.x + x.y * y.y + x.z * y.z + x.w * y.w;
      }
#pragma unroll
      for (int off = 32; off > 0; off >>= 1) s += __shfl_down(s, off, 64);
      if (l == 0) ht[bb * 1024 + h] = s;
    }
  }
}

// ---- main GEMM: C = tanh(A.B^T + ht[m%64][n]), 256x128 tile, 8 waves ----
__global__ __launch_bounds__(512, 4) void gemm_tanh(
    const unsigned short* __restrict__ A, const unsigned short* __restrict__ B,
    const float* __restrict__ ht, float* __restrict__ out0,
    float* __restrict__ out1) {
  __shared__ unsigned short As[BM * BKT];  // 16 KiB
  __shared__ unsigned short Bs[BN * BKT];  // 8 KiB

  // XCD-bijective swizzle (nwg = 1024 % 8 == 0); A-panel sharers co-XCD.
  int bid = blockIdx.x;
  int swz = (bid & 7) * 128 + (bid >> 3);
  int bm = swz >> 3;  // 0..127
  int bn = swz & 7;   // 0..7

  int tid = threadIdx.x;
  int lane = tid & 63, wid = tid >> 6;
  int wr = wid >> 1, wc = wid & 1;  // 4 x 2 waves, each 64x64 output
  int fr = lane & 15, kq = lane >> 4;

  // Staging: A = 1024 chunks (256 rows x 4 slots), B = 512 chunks.
  // Thread t stages A chunks t, t+512 and B chunk t. LDS dest linear;
  // global source pre-swizzled, so source addrs are linear too.
  int c1 = tid + 512;
  const unsigned short* gA0 =
      A + (size_t)(bm * BM + (tid >> 2)) * 1024 + (tid & 3) * 8;
  const unsigned short* gA1 =
      A + (size_t)(bm * BM + (c1 >> 2)) * 1024 + (tid & 3) * 8;
  const unsigned short* gB0 =
      B + (size_t)(bn * BN + (tid >> 2)) * 1024 + (tid & 3) * 8;

  f32x4 acc[4][4] = {};

  for (int ks = 0; ks < K_D; ks += BKT) {
    async16(gA0 + ks, &As[tid * 8]);
    async16(gA1 + ks, &As[c1 * 8]);
    async16(gB0 + ks, &Bs[tid * 8]);
    __syncthreads();  // drains vmcnt+lgkmcnt before LDS reads

    bf16x8 af[4], bg[4];
#pragma unroll
    for (int mi = 0; mi < 4; ++mi) {
      int ra = wr * 64 + mi * 16 + fr;
      af[mi] = *reinterpret_cast<const bf16x8*>(
          &As[ra * BKT + (kq ^ ((ra >> 1) & 3)) * 8]);
    }
#pragma unroll
    for (int ni = 0; ni < 4; ++ni) {
      int rb = wc * 64 + ni * 16 + fr;
      bg[ni] = *reinterpret_cast<const bf16x8*>(
          &Bs[rb * BKT + (kq ^ ((rb >> 1) & 3)) * 8]);
    }
#pragma unroll
    for (int mi = 0; mi < 4; ++mi)
#pragma unroll
      for (int ni = 0; ni < 4; ++ni)
        acc[mi][ni] = __builtin_amdgcn_mfma_f32_16x16x32_bf16(
            af[mi], bg[ni], acc[mi][ni], 0, 0, 0);
    __syncthreads();  // before next stage overwrites LDS
  }

  // Epilogue: y = tanh(acc + ht[m%64][n]); out0 always, out1 for last 64 rows.
  const int nbase = bn * BN + wc * 64;
#pragma unroll
  for (int mi = 0; mi < 4; ++mi) {
#pragma unroll
    for (int r = 0; r < 4; ++r) {
      int mloc = wr * 64 + mi * 16 + kq * 4 + r;  // 0..255
      size_t m = (size_t)bm * BM + mloc;
      int b = mloc & 63;  // m % 64 (BM multiple of 64)
#pragma unroll
      for (int ni = 0; ni < 4; ++ni) {
        int n = nbase + ni * 16 + fr;
        float x = acc[mi][ni][r] + ht[b * 1024 + n];
        float e = __expf(2.0f * x);
        float y = 1.0f - 2.0f / (e + 1.0f);  // tanh(x), safe at +-inf
        out0[m * 1024 + n] = y;
        if (m >= (size_t)(M_TOT - 64))
          out1[(m - (M_TOT - 64)) * 1024 + n] = y;
      }
    }
  }
}

extern "C" void kernel_launch(void* const* d_in, const int* in_sizes, int n_in,
                              void* d_out, int out_size, void* d_ws,
                              size_t ws_size, hipStream_t stream) {
  (void)in_sizes; (void)n_in; (void)out_size; (void)ws_size;
  const float* X  = (const float*)d_in[0];  // [512,64,1024] = [32768,1024]
  const float* hs = (const float*)d_in[1];  // [64,1024]
  const float* W  = (const float*)d_in[2];  // [1024,1024]
  const float* Hm = (const float*)d_in[3];  // [1024,1024]
  float* out0 = (float*)d_out;               // [32768,1024]
  float* out1 = out0 + (size_t)M_TOT * N_D;  // [64,1024]

  // ws layout: Xbf (64 MiB) | Wbf (2 MiB) | hterm (256 KiB)
  unsigned short* Xbf = (unsigned short*)d_ws;
  unsigned short* Wbf = Xbf + (size_t)M_TOT * K_D;
  float* hterm = (float*)(Wbf + (size_t)N_D * K_D);

  prep_kernel<<<PREP_GRID, 256, 0, stream>>>(X, Xbf, W, Wbf, hs, Hm, hterm);
  gemm_tanh<<<(M_TOT / BM) * (N_D / BN), 512, 0, stream>>>(Xbf, Wbf, hterm,
                                                           out0, out1);
}